// Round 10
// baseline (369.599 us; speedup 1.0000x reference)
//
#include <hip/hip_runtime.h>
#include <cstdint>
#include <cstddef>

typedef __attribute__((ext_vector_type(8))) short bf16x8;
typedef __attribute__((ext_vector_type(16))) float f32x16;
typedef unsigned short u16;
typedef unsigned int u32;

__device__ __forceinline__ u16 f2bf(float f) {
  u32 u = __float_as_uint(f);
  u32 r = (u + 0x7fffu + ((u >> 16) & 1u)) >> 16;
  return (u16)r;
}
__device__ __forceinline__ float bf2f(u16 h) {
  return __uint_as_float(((u32)h) << 16);
}
__device__ __forceinline__ float fsilu(float v) { return v / (1.f + __expf(-v)); }
__device__ __forceinline__ float fsigmoid(float v) { return 1.f / (1.f + __expf(-v)); }
// tanh(v) = 1 - 2/(e^{2v}+1); exact at +-inf, no branches
__device__ __forceinline__ float ftanh(float v) {
  return 1.f - 2.f / (__expf(2.f * v) + 1.f);
}

__device__ __forceinline__ void glds16(const void* g, void* l) {
  __builtin_amdgcn_global_load_lds(
      (const __attribute__((address_space(1))) void*)g,
      (__attribute__((address_space(3))) void*)l, 16, 0, 0);
}

#define FENCE_MEM() asm volatile("" ::: "memory")
#define BAR() __builtin_amdgcn_s_barrier()
#define VMCNT(n) asm volatile("s_waitcnt vmcnt(" #n ")" ::: "memory")
// counted lgkm wait + sched fence (rule #18)
#define LGKMW(n)                                        \
  do {                                                  \
    asm volatile("s_waitcnt lgkmcnt(" #n ")" ::: "memory"); \
    __builtin_amdgcn_sched_barrier(0);                  \
  } while (0)

// ---------------- cast / transpose ----------------

__global__ __launch_bounds__(256) void cast_bf16_vec(const float* __restrict__ src,
                                                     u16* __restrict__ dst, int n4) {
  int i = blockIdx.x * 256 + threadIdx.x;
  if (i >= n4) return;
  const float4 v = ((const float4*)src)[i];
  ushort4 o;
  o.x = f2bf(v.x); o.y = f2bf(v.y); o.z = f2bf(v.z); o.w = f2bf(v.w);
  ((ushort4*)dst)[i] = o;
}

// src: R x C f32 row-major  ->  dst: C x R bf16 row-major
__global__ void transpose_cast(const float* __restrict__ src, u16* __restrict__ dst,
                               int R, int C) {
  __shared__ float tile[32][33];
  int bx = blockIdx.x * 32;  // col base
  int by = blockIdx.y * 32;  // row base
  int tx = threadIdx.x, ty = threadIdx.y;  // (32,8)
#pragma unroll
  for (int i = 0; i < 4; ++i)
    tile[ty + i * 8][tx] = src[(size_t)(by + ty + i * 8) * C + bx + tx];
  __syncthreads();
#pragma unroll
  for (int i = 0; i < 4; ++i)
    dst[(size_t)(bx + ty + i * 8) * R + by + tx] = f2bf(tile[tx][ty + i * 8]);
}

// ---------------- 256x256 pipelined GEMM (A: MxK bf16 rm, Bt: NxK bf16 rm) --
// EPI 0: silu -> bf16     EPI 1: +bias, col<1024 ? tanh : sigmoid -> bf16
// r6 skeleton (best measured) but with mfma_f32_32x32x16_bf16: 8 waves
// (2M x 4N), per-wave 128x64 = 4x2 frags of 32x32, BK=64 = 4 K-slices of 16.
// 32 MFMA + 24 ds_read_b128 per wave per K-tile (vs 64 MFMA at 16x16 shape);
// measured 32x32 pipe is 13-17% faster (m119) at identical LDS bytes.
// A frag: row=lane&31, k=(lane>>5)*8+j.  B frag: col=lane&31, same k.
// C/D: col=lane&31, row=(reg&3)+8*(reg>>2)+4*(lane>>5)  [HW-verified m74/m101]
// Swizzle: 16B chunk c stored at c^(row&7); row&7 == lane&7 for all frags.

template <int EPI>
__global__ __launch_bounds__(512, 2) void gemm256(const u16* __restrict__ A,
                                                  const u16* __restrict__ Bt,
                                                  u16* __restrict__ Co,
                                                  const float* __restrict__ bias,
                                                  int M, int N, int K) {
  __shared__ char lds[131072];  // buf b: A at b*65536, B at b*65536+32768
  const int tid = threadIdx.x;
  const int lane = tid & 63;
  const int wid = tid >> 6;
  const int wr = wid >> 2;  // 0..1
  const int wc = wid & 3;   // 0..3

  // XCD-aware bijective swizzle (nwg = 512, %8 == 0)
  const int gx = gridDim.x;
  const int nwg = gx * gridDim.y;
  const int bid = blockIdx.y * gx + blockIdx.x;
  const int swz = (bid & 7) * (nwg >> 3) + (bid >> 3);
  const long bm = (long)(swz / gx) * 256;
  const long bn = (long)(swz % gx) * 256;

  const int NT = K >> 6;

  // ---- staging precompute ----
  const int r0 = tid >> 3, c0p = tid & 7;
  const int r1 = r0 + 64;
  const int gA0 = (r0 & 63) + ((r0 >> 6) << 7);
  const int gA1 = (r1 & 63) + ((r1 >> 6) << 7);
  const int gB0 = (r0 & 31) + ((r0 >> 5) << 6);
  const int gB1 = (r1 & 31) + ((r1 >> 5) << 6);
  const int cA0 = c0p ^ (r0 & 7);  // swizzled source chunk
  const size_t srcA0 = (size_t)(bm + gA0) * K + cA0 * 8;
  const size_t srcA1 = (size_t)(bm + gA1) * K + cA0 * 8;
  const size_t srcB0 = (size_t)(bn + gB0) * K + cA0 * 8;
  const size_t srcB1 = (size_t)(bn + gB1) * K + cA0 * 8;
  const int dstA0 = gA0 * 128 + c0p * 16;
  const int dstA1 = gA1 * 128 + c0p * 16;
  const int dstB0 = 32768 + gB0 * 128 + c0p * 16;
  const int dstB1 = 32768 + gB1 * 128 + c0p * 16;
  const size_t halfA = (size_t)64 * K;  // elements
  const size_t halfB = (size_t)32 * K;

  // stage one half-tile pair (2 glds): pair 0..3 = Ah0, Ah1, Bh0, Bh1
#define STAGE_P(buf, t, pair)                                                        \
  do {                                                                               \
    if ((pair) == 0) {                                                               \
      glds16(A + srcA0 + (size_t)(t) * 64, lds + (buf) * 65536 + dstA0);             \
      glds16(A + srcA1 + (size_t)(t) * 64, lds + (buf) * 65536 + dstA1);             \
    } else if ((pair) == 1) {                                                        \
      glds16(A + srcA0 + halfA + (size_t)(t) * 64,                                   \
             lds + (buf) * 65536 + dstA0 + 8192);                                    \
      glds16(A + srcA1 + halfA + (size_t)(t) * 64,                                   \
             lds + (buf) * 65536 + dstA1 + 8192);                                    \
    } else if ((pair) == 2) {                                                        \
      glds16(Bt + srcB0 + (size_t)(t) * 64, lds + (buf) * 65536 + dstB0);            \
      glds16(Bt + srcB1 + (size_t)(t) * 64, lds + (buf) * 65536 + dstB1);            \
    } else {                                                                         \
      glds16(Bt + srcB0 + halfB + (size_t)(t) * 64,                                  \
             lds + (buf) * 65536 + dstB0 + 4096);                                    \
      glds16(Bt + srcB1 + halfB + (size_t)(t) * 64,                                  \
             lds + (buf) * 65536 + dstB1 + 4096);                                    \
    }                                                                                \
  } while (0)

  // ---- ds_read bases: chunk for K-slice ks = (ks*2 + (lane>>5)) ^ (lane&7) --
  const int l31 = lane & 31, l7 = lane & 7, kg = lane >> 5;
  const int abase = (wr * 128 + l31) * 128;
  const int bbase = 32768 + (wc * 64 + l31) * 128;
  const int cof0 = ((0 + kg) ^ l7) * 16;
  const int cof1 = ((2 + kg) ^ l7) * 16;
  const int cof2 = ((4 + kg) ^ l7) * 16;
  const int cof3 = ((6 + kg) ^ l7) * 16;

  f32x16 acc[4][2] = {};

#define COF(ks) ((ks) == 0 ? cof0 : (ks) == 1 ? cof1 : (ks) == 2 ? cof2 : cof3)

#define READ_A(dst, ks)                                                              \
  do {                                                                               \
    _Pragma("unroll") for (int mf = 0; mf < 4; ++mf)                                 \
        dst[mf] = *(const bf16x8*)(base + abase + mf * 32 * 128 + COF(ks));          \
  } while (0)

  // 8 independent MFMAs per K-slice group (all distinct acc)
#define MFMA_G(ks, af)                                                               \
  do {                                                                               \
    __builtin_amdgcn_s_setprio(1);                                                   \
    _Pragma("unroll") for (int mf = 0; mf < 4; ++mf)                                 \
        _Pragma("unroll") for (int nf = 0; nf < 2; ++nf) {                           \
      acc[mf][nf] = __builtin_amdgcn_mfma_f32_32x32x16_bf16(                         \
          af[mf], bfr[nf][ks], acc[mf][nf], 0, 0, 0);                                \
    }                                                                                \
    __builtin_amdgcn_s_setprio(0);                                                   \
  } while (0)

  // ---- prologue: stage tile 0 into buf 0 ----
  STAGE_P(0, 0, 0);
  STAGE_P(0, 0, 1);
  STAGE_P(0, 0, 2);
  STAGE_P(0, 0, 3);
  VMCNT(0);
  FENCE_MEM();
  BAR();
  FENCE_MEM();

  for (int t = 0; t < NT; ++t) {
    const int p = t & 1;
    const char* base = lds + p * 65536;
    const bool s1 = (t + 1) < NT;

    bf16x8 bfr[2][4];                // all B frags for the K-tile (8 reads)
    bf16x8 ax[4], ay[4];             // A double-buffer (named, static idx)

    // issue B all (8) + A ks0 (4) + A ks1 (4)  -> 16 outstanding ds_reads
#pragma unroll
    for (int nf = 0; nf < 2; ++nf) {
      bfr[nf][0] = *(const bf16x8*)(base + bbase + nf * 32 * 128 + cof0);
      bfr[nf][1] = *(const bf16x8*)(base + bbase + nf * 32 * 128 + cof1);
      bfr[nf][2] = *(const bf16x8*)(base + bbase + nf * 32 * 128 + cof2);
      bfr[nf][3] = *(const bf16x8*)(base + bbase + nf * 32 * 128 + cof3);
    }
    READ_A(ax, 0);
    READ_A(ay, 1);
    if (s1) STAGE_P(p ^ 1, t + 1, 0);
    FENCE_MEM();
    LGKMW(4);        // B + A(ks0) complete; A(ks1) in flight
    MFMA_G(0, ax);
    READ_A(ax, 2);   // issue under ks0's MFMA window
    if (s1) STAGE_P(p ^ 1, t + 1, 1);
    FENCE_MEM();
    LGKMW(4);        // A(ks1) complete; A(ks2) in flight
    MFMA_G(1, ay);
    READ_A(ay, 3);
    if (s1) STAGE_P(p ^ 1, t + 1, 2);
    FENCE_MEM();
    LGKMW(4);        // A(ks2) complete; A(ks3) in flight
    MFMA_G(2, ax);
    if (s1) STAGE_P(p ^ 1, t + 1, 3);
    FENCE_MEM();
    LGKMW(0);        // A(ks3) complete
    MFMA_G(3, ay);

    // tile end: next tile's stage loads must be in LDS before any wave
    // reads buf p^1
    VMCNT(0);
    FENCE_MEM();
    BAR();
    FENCE_MEM();
  }

  // ---- epilogue (32x32 C/D layout) ----
#pragma unroll
  for (int mf = 0; mf < 4; ++mf) {
#pragma unroll
    for (int nf = 0; nf < 2; ++nf) {
      const long col = bn + wc * 64 + nf * 32 + l31;
      float badd = (EPI == 1) ? bias[col] : 0.f;
#pragma unroll
      for (int reg = 0; reg < 16; ++reg) {
        const long row =
            bm + wr * 128 + mf * 32 + (reg & 3) + 8 * (reg >> 2) + 4 * kg;
        float v = acc[mf][nf][reg];
        if (EPI == 0) {
          v = fsilu(v);
        } else {
          v += badd;
          v = (col < 1024) ? ftanh(v) : fsigmoid(v);
        }
        Co[row * (long)N + col] = f2bf(v);
      }
    }
  }
#undef STAGE_P
#undef READ_A
#undef MFMA_G
#undef COF
}

// ---------------- gated scan ----------------
// sa layout: (B*T) x 2048 bf16; [.,0:1024)=tanh(theta), [.,1024:2048)=sigmoid(alpha)
// stage1 (vectorized, 4 d/thread): per (b,chunk,d) 64-step affine summary
// (A,B) and 63-step (A63,B63).
// scan3_fused: one block per (b,chunk); locally scans (cA,cB) chain for its
// chunk start state (stage2 folded in); replay + conv + silu + residual +
// LN + L2 with one 5-value block reduction per row.

__global__ __launch_bounds__(256) void scan_stage1(const u16* __restrict__ sa,
                                                   float* __restrict__ cA,
                                                   float* __restrict__ cB,
                                                   float* __restrict__ cA63,
                                                   float* __restrict__ cB63) {
  const int tid = blockIdx.x * 256 + threadIdx.x;  // 0..65535
  const int d0 = (tid & 255) * 4;
  const int chunk = (tid >> 8) & 63;
  const int b = tid >> 14;
  const size_t row0 = (size_t)(b * 4096 + chunk * 64);
  const u16* ps = sa + row0 * 2048 + d0;
  float Ac[4] = {1.f, 1.f, 1.f, 1.f};
  float Bc[4] = {0.f, 0.f, 0.f, 0.f};
#pragma unroll 4
  for (int t = 0; t < 63; ++t) {
    const ushort4 sv = *(const ushort4*)(ps + (size_t)t * 2048);
    const ushort4 av = *(const ushort4*)(ps + (size_t)t * 2048 + 1024);
    const float s[4] = {bf2f(sv.x), bf2f(sv.y), bf2f(sv.z), bf2f(sv.w)};
    const float a[4] = {bf2f(av.x), bf2f(av.y), bf2f(av.z), bf2f(av.w)};
#pragma unroll
    for (int j = 0; j < 4; ++j) {
      Bc[j] = a[j] * Bc[j] + (1.f - a[j]) * s[j];
      Ac[j] *= a[j];
    }
  }
  const size_t cidx = (size_t)(b * 64 + chunk) * 1024 + d0;
  *(float4*)(cA63 + cidx) = make_float4(Ac[0], Ac[1], Ac[2], Ac[3]);
  *(float4*)(cB63 + cidx) = make_float4(Bc[0], Bc[1], Bc[2], Bc[3]);
  {
    const ushort4 sv = *(const ushort4*)(ps + (size_t)63 * 2048);
    const ushort4 av = *(const ushort4*)(ps + (size_t)63 * 2048 + 1024);
    const float s[4] = {bf2f(sv.x), bf2f(sv.y), bf2f(sv.z), bf2f(sv.w)};
    const float a[4] = {bf2f(av.x), bf2f(av.y), bf2f(av.z), bf2f(av.w)};
#pragma unroll
    for (int j = 0; j < 4; ++j) {
      Bc[j] = a[j] * Bc[j] + (1.f - a[j]) * s[j];
      Ac[j] *= a[j];
    }
  }
  *(float4*)(cA + cidx) = make_float4(Ac[0], Ac[1], Ac[2], Ac[3]);
  *(float4*)(cB + cidx) = make_float4(Bc[0], Bc[1], Bc[2], Bc[3]);
}

// Fused: local chunk-chain scan (ex-stage2) + replay + causal depthwise
// conv(k=3) + silu + residual + LN + L2.
// Block = (b, chunk): 256 threads x 4 d each. Conv taps h[t-1], h[t-2] in
// registers; boundary taps via local scan of (cA,cB) [2 MB, L2/L3-resident]
// and h[c*64-2] = A63[c-1]*hstart[c-1] + B63[c-1].
// LN+L2 in ONE 5-value block reduction per row:
//   nrm^2 = rstd^2*(G2-2mu G1+mu^2 Sg2) + 2 rstd*(GB-mu Sgb) + Sb2.
__global__ __launch_bounds__(256) void scan3_fused(
    const u16* __restrict__ sa, const float* __restrict__ cA,
    const float* __restrict__ cB, const float* __restrict__ cA63,
    const float* __restrict__ cB63, const float* __restrict__ cw,
    const float* __restrict__ gamma, const float* __restrict__ beta,
    float* __restrict__ out) {
  const int blk = blockIdx.x;  // b*64 + c, 0..255
  const int c = blk & 63;
  const int tid = threadIdx.x;
  const int lane = tid & 63, wid = tid >> 6;
  const int d0 = tid * 4;
  const size_t m0 = (size_t)(blk >> 6) * 4096 + (size_t)c * 64;

  __shared__ float red[4][8];

  // per-thread params
  const float4 gv = *(const float4*)(gamma + d0);
  const float4 bv = *(const float4*)(beta + d0);
  const float g[4] = {gv.x, gv.y, gv.z, gv.w};
  const float be[4] = {bv.x, bv.y, bv.z, bv.w};
  float w0[4], w1[4], w2[4];
#pragma unroll
  for (int j = 0; j < 4; ++j) {
    w0[j] = cw[(d0 + j) * 3];
    w1[j] = cw[(d0 + j) * 3 + 1];
    w2[j] = cw[(d0 + j) * 3 + 2];
  }

  // local chunk-chain scan (stage2 folded in): hstart for chunk c and c-1
  float hcur[4] = {0.f, 0.f, 0.f, 0.f};
  float hp[4] = {0.f, 0.f, 0.f, 0.f};
  const size_t chbase = (size_t)(blk - c) * 1024 + d0;  // (b*64+0)*1024+d0
  for (int i = 0; i < c; ++i) {
    const float4 a4 = *(const float4*)(cA + chbase + (size_t)i * 1024);
    const float4 b4 = *(const float4*)(cB + chbase + (size_t)i * 1024);
    if (i == c - 1) {
      hp[0] = hcur[0]; hp[1] = hcur[1]; hp[2] = hcur[2]; hp[3] = hcur[3];
    }
    hcur[0] = a4.x * hcur[0] + b4.x;
    hcur[1] = a4.y * hcur[1] + b4.y;
    hcur[2] = a4.z * hcur[2] + b4.z;
    hcur[3] = a4.w * hcur[3] + b4.w;
  }
  float h1v[4] = {hcur[0], hcur[1], hcur[2], hcur[3]};  // h[t0-1]
  float h2v[4] = {0.f, 0.f, 0.f, 0.f};                  // h[t0-2]
  if (c > 0) {
    const size_t pidx = (size_t)(blk - 1) * 1024 + d0;
    const float4 a63 = *(const float4*)(cA63 + pidx);
    const float4 b63 = *(const float4*)(cB63 + pidx);
    h2v[0] = a63.x * hp[0] + b63.x;
    h2v[1] = a63.y * hp[1] + b63.y;
    h2v[2] = a63.z * hp[2] + b63.z;
    h2v[3] = a63.w * hp[3] + b63.w;
  }

  // block constants Sg2, Sgb, Sb2 (one 3-value reduction)
  float sg2 = 0.f, sgb = 0.f, sb2 = 0.f;
#pragma unroll
  for (int j = 0; j < 4; ++j) {
    sg2 += g[j] * g[j];
    sgb += g[j] * be[j];
    sb2 += be[j] * be[j];
  }
#pragma unroll
  for (int o = 32; o > 0; o >>= 1) {
    sg2 += __shfl_down(sg2, o);
    sgb += __shfl_down(sgb, o);
    sb2 += __shfl_down(sb2, o);
  }
  if (lane == 0) { red[wid][5] = sg2; red[wid][6] = sgb; red[wid][7] = sb2; }
  __syncthreads();
  const float Sg2 = red[0][5] + red[1][5] + red[2][5] + red[3][5];
  const float Sgb = red[0][6] + red[1][6] + red[2][6] + red[3][6];
  const float Sb2 = red[0][7] + red[1][7] + red[2][7] + red[3][7];
  __syncthreads();

  const u16* ps = sa + m0 * 2048 + d0;
  ushort4 sv = *(const ushort4*)(ps);
  ushort4 av = *(const ushort4*)(ps + 1024);

  for (int t = 0; t < 64; ++t) {
    ushort4 svn, avn;
    if (t + 1 < 64) {
      svn = *(const ushort4*)(ps + (size_t)(t + 1) * 2048);
      avn = *(const ushort4*)(ps + (size_t)(t + 1) * 2048 + 1024);
    }
    const float sarr[4] = {bf2f(sv.x), bf2f(sv.y), bf2f(sv.z), bf2f(sv.w)};
    const float aarr[4] = {bf2f(av.x), bf2f(av.y), bf2f(av.z), bf2f(av.w)};
    float y[4];
    float s1 = 0.f, s2 = 0.f, g1 = 0.f, g2 = 0.f, gb = 0.f;
#pragma unroll
    for (int j = 0; j < 4; ++j) {
      const float a = aarr[j];
      const float h = a * h1v[j] + (1.f - a) * sarr[j];
      float cb = w0[j] * h2v[j] + w1[j] * h1v[j] + w2[j] * h;
      cb = fsilu(cb);
      y[j] = h + 0.1f * cb;
      h2v[j] = h1v[j];
      h1v[j] = h;
      s1 += y[j];
      s2 += y[j] * y[j];
      const float gy = g[j] * y[j];
      g1 += g[j] * gy;
      g2 += gy * gy;
      gb += be[j] * gy;
    }
    // one 5-value block reduction
    float v0 = s1, v1 = s2, v2 = g1, v3 = g2, v4 = gb;
#pragma unroll
    for (int o = 32; o > 0; o >>= 1) {
      v0 += __shfl_down(v0, o);
      v1 += __shfl_down(v1, o);
      v2 += __shfl_down(v2, o);
      v3 += __shfl_down(v3, o);
      v4 += __shfl_down(v4, o);
    }
    if (lane == 0) {
      red[wid][0] = v0; red[wid][1] = v1; red[wid][2] = v2;
      red[wid][3] = v3; red[wid][4] = v4;
    }
    __syncthreads();
    const float S1 = red[0][0] + red[1][0] + red[2][0] + red[3][0];
    const float S2 = red[0][1] + red[1][1] + red[2][1] + red[3][1];
    const float G1 = red[0][2] + red[1][2] + red[2][2] + red[3][2];
    const float G2 = red[0][3] + red[1][3] + red[2][3] + red[3][3];
    const float GB = red[0][4] + red[1][4] + red[2][4] + red[3][4];
    const float mu = S1 * (1.f / 1024.f);
    const float var = S2 * (1.f / 1024.f) - mu * mu;
    const float rstd = rsqrtf(var + 1e-5f);
    const float sge2 = G2 - 2.f * mu * G1 + mu * mu * Sg2;
    const float sgbe = GB - mu * Sgb;
    const float nrm2 = rstd * rstd * sge2 + 2.f * rstd * sgbe + Sb2;
    const float nrm = sqrtf(fmaxf(nrm2, 0.f));
    const float scale = 1.f / fmaxf(nrm, 1e-12f);
    float4 o4;
    o4.x = (g[0] * (y[0] - mu) * rstd + be[0]) * scale;
    o4.y = (g[1] * (y[1] - mu) * rstd + be[1]) * scale;
    o4.z = (g[2] * (y[2] - mu) * rstd + be[2]) * scale;
    o4.w = (g[3] * (y[3] - mu) * rstd + be[3]) * scale;
    *(float4*)(out + (m0 + t) * 1024 + d0) = o4;
    __syncthreads();  // protect red[] before next row's writes
    sv = svn;
    av = avn;
  }
}

// ---------------- launch ----------------

extern "C" void kernel_launch(void* const* d_in, const int* in_sizes, int n_in,
                              void* d_out, int out_size, void* d_ws, size_t ws_size,
                              hipStream_t stream) {
  const float* x = (const float*)d_in[0];
  const float* W1 = (const float*)d_in[1];
  const float* W2 = (const float*)d_in[2];
  const float* b2 = (const float*)d_in[3];
  const float* cw = (const float*)d_in[4];
  const float* gamma = (const float*)d_in[5];
  const float* beta = (const float*)d_in[6];
  float* out = (float*)d_out;
  char* ws = (char*)d_ws;

  // workspace layout (bytes):
  // [0,32M)    xb (bf16 x) -- dead after gemm1; reused by scan buffers:
  //            cA@0, cB@1M, cA63@2M, cB63@3M (each 1MB)
  // [32M,36M)  w1t   [36M,44M) w2t
  // [44M,108M) h1 (bf16 16384x2048) -- gemm2 input
  // [108M,172M) sa (bf16 16384x2048) tanh(theta) | sigmoid(alpha)
  u16* xb = (u16*)(ws);
  u16* w1t = (u16*)(ws + 33554432);
  u16* w2t = (u16*)(ws + 37748736);
  u16* h1 = (u16*)(ws + 46137344);
  u16* sa = (u16*)(ws + 113246208);
  float* cA = (float*)(ws);
  float* cB = (float*)(ws + 1048576);
  float* cA63 = (float*)(ws + 2097152);
  float* cB63 = (float*)(ws + 3145728);

  cast_bf16_vec<<<16384, 256, 0, stream>>>(x, xb, 4194304);
  transpose_cast<<<dim3(64, 32), dim3(32, 8), 0, stream>>>(W1, w1t, 1024, 2048);
  transpose_cast<<<dim3(64, 64), dim3(32, 8), 0, stream>>>(W2, w2t, 2048, 2048);
  gemm256<0><<<dim3(8, 64), 512, 0, stream>>>(xb, w1t, h1, nullptr, 16384, 2048, 1024);
  gemm256<1><<<dim3(8, 64), 512, 0, stream>>>(h1, w2t, sa, b2, 16384, 2048, 2048);
  scan_stage1<<<256, 256, 0, stream>>>(sa, cA, cB, cA63, cB63);
  scan3_fused<<<256, 256, 0, stream>>>(sa, cA, cB, cA63, cB63, cw, gamma, beta, out);
}

// Round 11
// 342.350 us; speedup vs baseline: 1.0796x; 1.0796x over previous
//
#include <hip/hip_runtime.h>
#include <cstdint>
#include <cstddef>

typedef __attribute__((ext_vector_type(8))) short bf16x8;
typedef __attribute__((ext_vector_type(4))) float f32x4;
typedef unsigned short u16;
typedef unsigned int u32;

__device__ __forceinline__ u16 f2bf(float f) {
  u32 u = __float_as_uint(f);
  u32 r = (u + 0x7fffu + ((u >> 16) & 1u)) >> 16;
  return (u16)r;
}
__device__ __forceinline__ float bf2f(u16 h) {
  return __uint_as_float(((u32)h) << 16);
}
__device__ __forceinline__ float fsilu(float v) { return v / (1.f + __expf(-v)); }
__device__ __forceinline__ float fsigmoid(float v) { return 1.f / (1.f + __expf(-v)); }
// tanh(v) = 1 - 2/(e^{2v}+1); exact at +-inf, no branches
__device__ __forceinline__ float ftanh(float v) {
  return 1.f - 2.f / (__expf(2.f * v) + 1.f);
}

__device__ __forceinline__ void glds16(const void* g, void* l) {
  __builtin_amdgcn_global_load_lds(
      (const __attribute__((address_space(1))) void*)g,
      (__attribute__((address_space(3))) void*)l, 16, 0, 0);
}

#define FENCE_MEM() asm volatile("" ::: "memory")
#define BAR() __builtin_amdgcn_s_barrier()
#define VMCNT(n) asm volatile("s_waitcnt vmcnt(" #n ")" ::: "memory")
// counted lgkm wait + sched fence (rule #18)
#define LGKMW(n)                                        \
  do {                                                  \
    asm volatile("s_waitcnt lgkmcnt(" #n ")" ::: "memory"); \
    __builtin_amdgcn_sched_barrier(0);                  \
  } while (0)

// ---------------- cast / transpose ----------------

__global__ __launch_bounds__(256) void cast_bf16_vec(const float* __restrict__ src,
                                                     u16* __restrict__ dst, int n4) {
  int i = blockIdx.x * 256 + threadIdx.x;
  if (i >= n4) return;
  const float4 v = ((const float4*)src)[i];
  ushort4 o;
  o.x = f2bf(v.x); o.y = f2bf(v.y); o.z = f2bf(v.z); o.w = f2bf(v.w);
  ((ushort4*)dst)[i] = o;
}

// src: R x C f32 row-major  ->  dst: C x R bf16 row-major
__global__ void transpose_cast(const float* __restrict__ src, u16* __restrict__ dst,
                               int R, int C) {
  __shared__ float tile[32][33];
  int bx = blockIdx.x * 32;  // col base
  int by = blockIdx.y * 32;  // row base
  int tx = threadIdx.x, ty = threadIdx.y;  // (32,8)
#pragma unroll
  for (int i = 0; i < 4; ++i)
    tile[ty + i * 8][tx] = src[(size_t)(by + ty + i * 8) * C + bx + tx];
  __syncthreads();
#pragma unroll
  for (int i = 0; i < 4; ++i)
    dst[(size_t)(bx + ty + i * 8) * R + by + tx] = f2bf(tile[tx][ty + i * 8]);
}

// ---------------- 256x256 pipelined GEMM (A: MxK bf16 rm, Bt: NxK bf16 rm) --
// EPI 0: silu -> bf16     EPI 1: +bias, col<1024 ? tanh : sigmoid -> bf16
// r8/r6 structure -- BEST MEASURED (gemm2 148.9us, 0 bank conflicts,
// MfmaUtil 40.5%): 8 waves (2M x 4N), 16x16x32 MFMA, BK=64, 128 KiB
// macro-dbuf, one barrier per K-tile, counted-lgkm in-wave pipeline,
// k-swept MFMA, staging spread across quadrants.
// Swizzle: 16B chunk c stored at c^(row&7) (pre-swizzled global source,
// linear glds dest, swizzled ds_read addr).
// NOTE r9 lesson: 32x32x16 MFMA shape broke the conflict-free layout
// (1.26e7 conflicts, -12%) -- do not switch shapes without re-deriving
// the phase-level bank pattern.

template <int EPI>
__global__ __launch_bounds__(512, 2) void gemm256(const u16* __restrict__ A,
                                                  const u16* __restrict__ Bt,
                                                  u16* __restrict__ Co,
                                                  const float* __restrict__ bias,
                                                  int M, int N, int K) {
  __shared__ char lds[131072];  // buf b: A at b*65536, B at b*65536+32768
  const int tid = threadIdx.x;
  const int lane = tid & 63;
  const int wid = tid >> 6;
  const int wr = wid >> 2;  // 0..1
  const int wc = wid & 3;   // 0..3

  // XCD-aware bijective swizzle (nwg = 512, %8 == 0)
  const int gx = gridDim.x;
  const int nwg = gx * gridDim.y;
  const int bid = blockIdx.y * gx + blockIdx.x;
  const int swz = (bid & 7) * (nwg >> 3) + (bid >> 3);
  const long bm = (long)(swz / gx) * 256;
  const long bn = (long)(swz % gx) * 256;

  const int NT = K >> 6;

  // ---- staging precompute ----
  const int r0 = tid >> 3, c0p = tid & 7;
  const int r1 = r0 + 64;
  const int gA0 = (r0 & 63) + ((r0 >> 6) << 7);
  const int gA1 = (r1 & 63) + ((r1 >> 6) << 7);
  const int gB0 = (r0 & 31) + ((r0 >> 5) << 6);
  const int gB1 = (r1 & 31) + ((r1 >> 5) << 6);
  const int cA0 = c0p ^ (r0 & 7);  // swizzled source chunk
  const size_t srcA0 = (size_t)(bm + gA0) * K + cA0 * 8;
  const size_t srcA1 = (size_t)(bm + gA1) * K + cA0 * 8;
  const size_t srcB0 = (size_t)(bn + gB0) * K + cA0 * 8;
  const size_t srcB1 = (size_t)(bn + gB1) * K + cA0 * 8;
  const int dstA0 = gA0 * 128 + c0p * 16;
  const int dstA1 = gA1 * 128 + c0p * 16;
  const int dstB0 = 32768 + gB0 * 128 + c0p * 16;
  const int dstB1 = 32768 + gB1 * 128 + c0p * 16;
  const size_t halfA = (size_t)64 * K;  // elements
  const size_t halfB = (size_t)32 * K;

  // stage one half-tile pair (2 glds): pair 0..3 = Ah0, Ah1, Bh0, Bh1
#define STAGE_P(buf, t, pair)                                                        \
  do {                                                                               \
    if ((pair) == 0) {                                                               \
      glds16(A + srcA0 + (size_t)(t) * 64, lds + (buf) * 65536 + dstA0);             \
      glds16(A + srcA1 + (size_t)(t) * 64, lds + (buf) * 65536 + dstA1);             \
    } else if ((pair) == 1) {                                                        \
      glds16(A + srcA0 + halfA + (size_t)(t) * 64,                                   \
             lds + (buf) * 65536 + dstA0 + 8192);                                    \
      glds16(A + srcA1 + halfA + (size_t)(t) * 64,                                   \
             lds + (buf) * 65536 + dstA1 + 8192);                                    \
    } else if ((pair) == 2) {                                                        \
      glds16(Bt + srcB0 + (size_t)(t) * 64, lds + (buf) * 65536 + dstB0);            \
      glds16(Bt + srcB1 + (size_t)(t) * 64, lds + (buf) * 65536 + dstB1);            \
    } else {                                                                         \
      glds16(Bt + srcB0 + halfB + (size_t)(t) * 64,                                  \
             lds + (buf) * 65536 + dstB0 + 4096);                                    \
      glds16(Bt + srcB1 + halfB + (size_t)(t) * 64,                                  \
             lds + (buf) * 65536 + dstB1 + 4096);                                    \
    }                                                                                \
  } while (0)

  // ---- ds_read bases (swizzled): chunk' = (kh*4 + (lane>>4)) ^ (lane&7) ----
  const int l15 = lane & 15, l3 = lane & 7, g4 = lane >> 4;
  const int aoff0 = (wr * 128 + l15) * 128 + ((g4 ^ l3) * 16);
  const int aoff1 = (wr * 128 + l15) * 128 + (((4 + g4) ^ l3) * 16);
  const int boff0 = 32768 + (wc * 64 + l15) * 128 + ((g4 ^ l3) * 16);
  const int boff1 = 32768 + (wc * 64 + l15) * 128 + (((4 + g4) ^ l3) * 16);

  f32x4 acc[8][4] = {};

#define READ_A(dst, q)                                                               \
  do {                                                                               \
    dst[0][0] = *(const bf16x8*)(base + aoff0 + ((q) * 2 + 0) * 2048);               \
    dst[0][1] = *(const bf16x8*)(base + aoff1 + ((q) * 2 + 0) * 2048);               \
    dst[1][0] = *(const bf16x8*)(base + aoff0 + ((q) * 2 + 1) * 2048);               \
    dst[1][1] = *(const bf16x8*)(base + aoff1 + ((q) * 2 + 1) * 2048);               \
  } while (0)

  // k-swept: 8 independent kh=0 MFMAs, then 8 kh=1 (producer 8 instrs back)
#define MFMA_Q(q, af)                                                                \
  do {                                                                               \
    __builtin_amdgcn_s_setprio(1);                                                   \
    _Pragma("unroll") for (int kh = 0; kh < 2; ++kh)                                 \
        _Pragma("unroll") for (int mm = 0; mm < 2; ++mm)                             \
            _Pragma("unroll") for (int nn = 0; nn < 4; ++nn) {                       \
      acc[(q) * 2 + mm][nn] = __builtin_amdgcn_mfma_f32_16x16x32_bf16(               \
          af[mm][kh], bfr[nn][kh], acc[(q) * 2 + mm][nn], 0, 0, 0);                  \
    }                                                                                \
    __builtin_amdgcn_s_setprio(0);                                                   \
  } while (0)

  // ---- prologue: stage tile 0 into buf 0 ----
  STAGE_P(0, 0, 0);
  STAGE_P(0, 0, 1);
  STAGE_P(0, 0, 2);
  STAGE_P(0, 0, 3);
  VMCNT(0);
  FENCE_MEM();
  BAR();
  FENCE_MEM();

  for (int t = 0; t < NT; ++t) {
    const int p = t & 1;
    const char* base = lds + p * 65536;
    const bool s1 = (t + 1) < NT;

    bf16x8 bfr[4][2];
    bf16x8 afx[2][2], afy[2][2];  // named double-buffer (static idx, rule #20)

    // issue B all (8 ds_read) + A q0 (4) + A q1 (4)  -> 16 outstanding
#pragma unroll
    for (int nn = 0; nn < 4; ++nn) {
      bfr[nn][0] = *(const bf16x8*)(base + boff0 + nn * 2048);
      bfr[nn][1] = *(const bf16x8*)(base + boff1 + nn * 2048);
    }
    READ_A(afx, 0);
    READ_A(afy, 1);
    if (s1) STAGE_P(p ^ 1, t + 1, 0);
    FENCE_MEM();
    LGKMW(4);        // B + A0 complete; A1 in flight
    MFMA_Q(0, afx);
    READ_A(afx, 2);  // issue under q0 completion window
    if (s1) STAGE_P(p ^ 1, t + 1, 1);
    FENCE_MEM();
    LGKMW(4);        // A1 complete; A2 in flight
    MFMA_Q(1, afy);
    READ_A(afy, 3);
    if (s1) STAGE_P(p ^ 1, t + 1, 2);
    FENCE_MEM();
    LGKMW(4);        // A2 complete; A3 in flight
    MFMA_Q(2, afx);
    if (s1) STAGE_P(p ^ 1, t + 1, 3);
    FENCE_MEM();
    LGKMW(0);        // A3 complete
    MFMA_Q(3, afy);

    // tile end: next tile's stage loads must be in LDS before any wave
    // reads buf p^1
    VMCNT(0);
    FENCE_MEM();
    BAR();
    FENCE_MEM();
  }

  // ---- epilogue ----
  const int erow = (lane >> 4) * 4;
  const int ecol = lane & 15;
#pragma unroll
  for (int mf = 0; mf < 8; ++mf) {
#pragma unroll
    for (int nf = 0; nf < 4; ++nf) {
      const long col = bn + wc * 64 + nf * 16 + ecol;
      float badd = (EPI == 1) ? bias[col] : 0.f;
#pragma unroll
      for (int j = 0; j < 4; ++j) {
        const long row = bm + wr * 128 + mf * 16 + erow + j;
        float v = acc[mf][nf][j];
        if (EPI == 0) {
          v = fsilu(v);
        } else {
          v += badd;
          v = (col < 1024) ? ftanh(v) : fsigmoid(v);
        }
        Co[row * (long)N + col] = f2bf(v);
      }
    }
  }
#undef STAGE_P
#undef READ_A
#undef MFMA_Q
}

// ---------------- gated scan ----------------
// sa layout: (B*T) x 2048 bf16; [.,0:1024)=tanh(theta), [.,1024:2048)=sigmoid(alpha)
// stage1 (vectorized, 4 d/thread): per (b,chunk,d) 64-step affine summary
// (A,B) and 63-step (A63,B63).
// scan3_fused: one block per (b,chunk); locally scans (cA,cB) chain for its
// chunk start state (stage2 folded in); replay + conv + silu + residual +
// LN + L2 with one 5-value block reduction per row.

__global__ __launch_bounds__(256) void scan_stage1(const u16* __restrict__ sa,
                                                   float* __restrict__ cA,
                                                   float* __restrict__ cB,
                                                   float* __restrict__ cA63,
                                                   float* __restrict__ cB63) {
  const int tid = blockIdx.x * 256 + threadIdx.x;  // 0..65535
  const int d0 = (tid & 255) * 4;
  const int chunk = (tid >> 8) & 63;
  const int b = tid >> 14;
  const size_t row0 = (size_t)(b * 4096 + chunk * 64);
  const u16* ps = sa + row0 * 2048 + d0;
  float Ac[4] = {1.f, 1.f, 1.f, 1.f};
  float Bc[4] = {0.f, 0.f, 0.f, 0.f};
#pragma unroll 4
  for (int t = 0; t < 63; ++t) {
    const ushort4 sv = *(const ushort4*)(ps + (size_t)t * 2048);
    const ushort4 av = *(const ushort4*)(ps + (size_t)t * 2048 + 1024);
    const float s[4] = {bf2f(sv.x), bf2f(sv.y), bf2f(sv.z), bf2f(sv.w)};
    const float a[4] = {bf2f(av.x), bf2f(av.y), bf2f(av.z), bf2f(av.w)};
#pragma unroll
    for (int j = 0; j < 4; ++j) {
      Bc[j] = a[j] * Bc[j] + (1.f - a[j]) * s[j];
      Ac[j] *= a[j];
    }
  }
  const size_t cidx = (size_t)(b * 64 + chunk) * 1024 + d0;
  *(float4*)(cA63 + cidx) = make_float4(Ac[0], Ac[1], Ac[2], Ac[3]);
  *(float4*)(cB63 + cidx) = make_float4(Bc[0], Bc[1], Bc[2], Bc[3]);
  {
    const ushort4 sv = *(const ushort4*)(ps + (size_t)63 * 2048);
    const ushort4 av = *(const ushort4*)(ps + (size_t)63 * 2048 + 1024);
    const float s[4] = {bf2f(sv.x), bf2f(sv.y), bf2f(sv.z), bf2f(sv.w)};
    const float a[4] = {bf2f(av.x), bf2f(av.y), bf2f(av.z), bf2f(av.w)};
#pragma unroll
    for (int j = 0; j < 4; ++j) {
      Bc[j] = a[j] * Bc[j] + (1.f - a[j]) * s[j];
      Ac[j] *= a[j];
    }
  }
  *(float4*)(cA + cidx) = make_float4(Ac[0], Ac[1], Ac[2], Ac[3]);
  *(float4*)(cB + cidx) = make_float4(Bc[0], Bc[1], Bc[2], Bc[3]);
}

// Fused: local chunk-chain scan (ex-stage2) + replay + causal depthwise
// conv(k=3) + silu + residual + LN + L2.
// Block = (b, chunk): 256 threads x 4 d each. Conv taps h[t-1], h[t-2] in
// registers; boundary taps via local scan of (cA,cB) [2 MB, L2/L3-resident]
// and h[c*64-2] = A63[c-1]*hstart[c-1] + B63[c-1].
// LN+L2 in ONE 5-value block reduction per row:
//   nrm^2 = rstd^2*(G2-2mu G1+mu^2 Sg2) + 2 rstd*(GB-mu Sgb) + Sb2.
__global__ __launch_bounds__(256) void scan3_fused(
    const u16* __restrict__ sa, const float* __restrict__ cA,
    const float* __restrict__ cB, const float* __restrict__ cA63,
    const float* __restrict__ cB63, const float* __restrict__ cw,
    const float* __restrict__ gamma, const float* __restrict__ beta,
    float* __restrict__ out) {
  const int blk = blockIdx.x;  // b*64 + c, 0..255
  const int c = blk & 63;
  const int tid = threadIdx.x;
  const int lane = tid & 63, wid = tid >> 6;
  const int d0 = tid * 4;
  const size_t m0 = (size_t)(blk >> 6) * 4096 + (size_t)c * 64;

  __shared__ float red[4][8];

  // per-thread params
  const float4 gv = *(const float4*)(gamma + d0);
  const float4 bv = *(const float4*)(beta + d0);
  const float g[4] = {gv.x, gv.y, gv.z, gv.w};
  const float be[4] = {bv.x, bv.y, bv.z, bv.w};
  float w0[4], w1[4], w2[4];
#pragma unroll
  for (int j = 0; j < 4; ++j) {
    w0[j] = cw[(d0 + j) * 3];
    w1[j] = cw[(d0 + j) * 3 + 1];
    w2[j] = cw[(d0 + j) * 3 + 2];
  }

  // local chunk-chain scan (stage2 folded in): hstart for chunk c and c-1
  float hcur[4] = {0.f, 0.f, 0.f, 0.f};
  float hp[4] = {0.f, 0.f, 0.f, 0.f};
  const size_t chbase = (size_t)(blk - c) * 1024 + d0;  // (b*64+0)*1024+d0
  for (int i = 0; i < c; ++i) {
    const float4 a4 = *(const float4*)(cA + chbase + (size_t)i * 1024);
    const float4 b4 = *(const float4*)(cB + chbase + (size_t)i * 1024);
    if (i == c - 1) {
      hp[0] = hcur[0]; hp[1] = hcur[1]; hp[2] = hcur[2]; hp[3] = hcur[3];
    }
    hcur[0] = a4.x * hcur[0] + b4.x;
    hcur[1] = a4.y * hcur[1] + b4.y;
    hcur[2] = a4.z * hcur[2] + b4.z;
    hcur[3] = a4.w * hcur[3] + b4.w;
  }
  float h1v[4] = {hcur[0], hcur[1], hcur[2], hcur[3]};  // h[t0-1]
  float h2v[4] = {0.f, 0.f, 0.f, 0.f};                  // h[t0-2]
  if (c > 0) {
    const size_t pidx = (size_t)(blk - 1) * 1024 + d0;
    const float4 a63 = *(const float4*)(cA63 + pidx);
    const float4 b63 = *(const float4*)(cB63 + pidx);
    h2v[0] = a63.x * hp[0] + b63.x;
    h2v[1] = a63.y * hp[1] + b63.y;
    h2v[2] = a63.z * hp[2] + b63.z;
    h2v[3] = a63.w * hp[3] + b63.w;
  }

  // block constants Sg2, Sgb, Sb2 (one 3-value reduction)
  float sg2 = 0.f, sgb = 0.f, sb2 = 0.f;
#pragma unroll
  for (int j = 0; j < 4; ++j) {
    sg2 += g[j] * g[j];
    sgb += g[j] * be[j];
    sb2 += be[j] * be[j];
  }
#pragma unroll
  for (int o = 32; o > 0; o >>= 1) {
    sg2 += __shfl_down(sg2, o);
    sgb += __shfl_down(sgb, o);
    sb2 += __shfl_down(sb2, o);
  }
  if (lane == 0) { red[wid][5] = sg2; red[wid][6] = sgb; red[wid][7] = sb2; }
  __syncthreads();
  const float Sg2 = red[0][5] + red[1][5] + red[2][5] + red[3][5];
  const float Sgb = red[0][6] + red[1][6] + red[2][6] + red[3][6];
  const float Sb2 = red[0][7] + red[1][7] + red[2][7] + red[3][7];
  __syncthreads();

  const u16* ps = sa + m0 * 2048 + d0;
  ushort4 sv = *(const ushort4*)(ps);
  ushort4 av = *(const ushort4*)(ps + 1024);

  for (int t = 0; t < 64; ++t) {
    ushort4 svn, avn;
    if (t + 1 < 64) {
      svn = *(const ushort4*)(ps + (size_t)(t + 1) * 2048);
      avn = *(const ushort4*)(ps + (size_t)(t + 1) * 2048 + 1024);
    }
    const float sarr[4] = {bf2f(sv.x), bf2f(sv.y), bf2f(sv.z), bf2f(sv.w)};
    const float aarr[4] = {bf2f(av.x), bf2f(av.y), bf2f(av.z), bf2f(av.w)};
    float y[4];
    float s1 = 0.f, s2 = 0.f, g1 = 0.f, g2 = 0.f, gb = 0.f;
#pragma unroll
    for (int j = 0; j < 4; ++j) {
      const float a = aarr[j];
      const float h = a * h1v[j] + (1.f - a) * sarr[j];
      float cb = w0[j] * h2v[j] + w1[j] * h1v[j] + w2[j] * h;
      cb = fsilu(cb);
      y[j] = h + 0.1f * cb;
      h2v[j] = h1v[j];
      h1v[j] = h;
      s1 += y[j];
      s2 += y[j] * y[j];
      const float gy = g[j] * y[j];
      g1 += g[j] * gy;
      g2 += gy * gy;
      gb += be[j] * gy;
    }
    // one 5-value block reduction
    float v0 = s1, v1 = s2, v2 = g1, v3 = g2, v4 = gb;
#pragma unroll
    for (int o = 32; o > 0; o >>= 1) {
      v0 += __shfl_down(v0, o);
      v1 += __shfl_down(v1, o);
      v2 += __shfl_down(v2, o);
      v3 += __shfl_down(v3, o);
      v4 += __shfl_down(v4, o);
    }
    if (lane == 0) {
      red[wid][0] = v0; red[wid][1] = v1; red[wid][2] = v2;
      red[wid][3] = v3; red[wid][4] = v4;
    }
    __syncthreads();
    const float S1 = red[0][0] + red[1][0] + red[2][0] + red[3][0];
    const float S2 = red[0][1] + red[1][1] + red[2][1] + red[3][1];
    const float G1 = red[0][2] + red[1][2] + red[2][2] + red[3][2];
    const float G2 = red[0][3] + red[1][3] + red[2][3] + red[3][3];
    const float GB = red[0][4] + red[1][4] + red[2][4] + red[3][4];
    const float mu = S1 * (1.f / 1024.f);
    const float var = S2 * (1.f / 1024.f) - mu * mu;
    const float rstd = rsqrtf(var + 1e-5f);
    const float sge2 = G2 - 2.f * mu * G1 + mu * mu * Sg2;
    const float sgbe = GB - mu * Sgb;
    const float nrm2 = rstd * rstd * sge2 + 2.f * rstd * sgbe + Sb2;
    const float nrm = sqrtf(fmaxf(nrm2, 0.f));
    const float scale = 1.f / fmaxf(nrm, 1e-12f);
    float4 o4;
    o4.x = (g[0] * (y[0] - mu) * rstd + be[0]) * scale;
    o4.y = (g[1] * (y[1] - mu) * rstd + be[1]) * scale;
    o4.z = (g[2] * (y[2] - mu) * rstd + be[2]) * scale;
    o4.w = (g[3] * (y[3] - mu) * rstd + be[3]) * scale;
    *(float4*)(out + (m0 + t) * 1024 + d0) = o4;
    __syncthreads();  // protect red[] before next row's writes
    sv = svn;
    av = avn;
  }
}

// ---------------- launch ----------------

extern "C" void kernel_launch(void* const* d_in, const int* in_sizes, int n_in,
                              void* d_out, int out_size, void* d_ws, size_t ws_size,
                              hipStream_t stream) {
  const float* x = (const float*)d_in[0];
  const float* W1 = (const float*)d_in[1];
  const float* W2 = (const float*)d_in[2];
  const float* b2 = (const float*)d_in[3];
  const float* cw = (const float*)d_in[4];
  const float* gamma = (const float*)d_in[5];
  const float* beta = (const float*)d_in[6];
  float* out = (float*)d_out;
  char* ws = (char*)d_ws;

  // workspace layout (bytes):
  // [0,32M)    xb (bf16 x) -- dead after gemm1; reused by scan buffers:
  //            cA@0, cB@1M, cA63@2M, cB63@3M (each 1MB)
  // [32M,36M)  w1t   [36M,44M) w2t
  // [44M,108M) h1 (bf16 16384x2048) -- gemm2 input
  // [108M,172M) sa (bf16 16384x2048) tanh(theta) | sigmoid(alpha)
  u16* xb = (u16*)(ws);
  u16* w1t = (u16*)(ws + 33554432);
  u16* w2t = (u16*)(ws + 37748736);
  u16* h1 = (u16*)(ws + 46137344);
  u16* sa = (u16*)(ws + 113246208);
  float* cA = (float*)(ws);
  float* cB = (float*)(ws + 1048576);
  float* cA63 = (float*)(ws + 2097152);
  float* cB63 = (float*)(ws + 3145728);

  cast_bf16_vec<<<16384, 256, 0, stream>>>(x, xb, 4194304);
  transpose_cast<<<dim3(64, 32), dim3(32, 8), 0, stream>>>(W1, w1t, 1024, 2048);
  transpose_cast<<<dim3(64, 64), dim3(32, 8), 0, stream>>>(W2, w2t, 2048, 2048);
  gemm256<0><<<dim3(8, 64), 512, 0, stream>>>(xb, w1t, h1, nullptr, 16384, 2048, 1024);
  gemm256<1><<<dim3(8, 64), 512, 0, stream>>>(h1, w2t, sa, b2, 16384, 2048, 2048);
  scan_stage1<<<256, 256, 0, stream>>>(sa, cA, cB, cA63, cB63);
  scan3_fused<<<256, 256, 0, stream>>>(sa, cA, cB, cA63, cB63, cw, gamma, beta, out);
}

// Round 14
// 325.455 us; speedup vs baseline: 1.1356x; 1.0519x over previous
//
#include <hip/hip_runtime.h>
#include <cstdint>
#include <cstddef>

typedef __attribute__((ext_vector_type(8))) short bf16x8;
typedef __attribute__((ext_vector_type(4))) float f32x4;
typedef unsigned short u16;
typedef unsigned int u32;

__device__ __forceinline__ u16 f2bf(float f) {
  u32 u = __float_as_uint(f);
  u32 r = (u + 0x7fffu + ((u >> 16) & 1u)) >> 16;
  return (u16)r;
}
__device__ __forceinline__ float bf2f(u16 h) {
  return __uint_as_float(((u32)h) << 16);
}
__device__ __forceinline__ float fsilu(float v) { return v / (1.f + __expf(-v)); }
__device__ __forceinline__ float fsigmoid(float v) { return 1.f / (1.f + __expf(-v)); }
// tanh(v) = 1 - 2/(e^{2v}+1); exact at +-inf, no branches
__device__ __forceinline__ float ftanh(float v) {
  return 1.f - 2.f / (__expf(2.f * v) + 1.f);
}

__device__ __forceinline__ void glds16(const void* g, void* l) {
  __builtin_amdgcn_global_load_lds(
      (const __attribute__((address_space(1))) void*)g,
      (__attribute__((address_space(3))) void*)l, 16, 0, 0);
}

#define FENCE_MEM() asm volatile("" ::: "memory")
#define BAR() __builtin_amdgcn_s_barrier()
#define VMCNT(n) asm volatile("s_waitcnt vmcnt(" #n ")" ::: "memory")
// counted lgkm wait + sched fence (rule #18)
#define LGKMW(n)                                        \
  do {                                                  \
    asm volatile("s_waitcnt lgkmcnt(" #n ")" ::: "memory"); \
    __builtin_amdgcn_sched_barrier(0);                  \
  } while (0)

// ---------------- cast / transpose ----------------

__global__ __launch_bounds__(256) void cast_bf16_vec(const float* __restrict__ src,
                                                     u16* __restrict__ dst, int n4) {
  int i = blockIdx.x * 256 + threadIdx.x;
  if (i >= n4) return;
  const float4 v = ((const float4*)src)[i];
  ushort4 o;
  o.x = f2bf(v.x); o.y = f2bf(v.y); o.z = f2bf(v.z); o.w = f2bf(v.w);
  ((ushort4*)dst)[i] = o;
}

// src: R x C f32 row-major  ->  dst: C x R bf16 row-major
__global__ void transpose_cast(const float* __restrict__ src, u16* __restrict__ dst,
                               int R, int C) {
  __shared__ float tile[32][33];
  int bx = blockIdx.x * 32;  // col base
  int by = blockIdx.y * 32;  // row base
  int tx = threadIdx.x, ty = threadIdx.y;  // (32,8)
#pragma unroll
  for (int i = 0; i < 4; ++i)
    tile[ty + i * 8][tx] = src[(size_t)(by + ty + i * 8) * C + bx + tx];
  __syncthreads();
#pragma unroll
  for (int i = 0; i < 4; ++i)
    dst[(size_t)(bx + ty + i * 8) * R + by + tx] = f2bf(tile[tx][ty + i * 8]);
}

// ---------------- 256x256 pipelined GEMM (A: MxK bf16 rm, Bt: NxK bf16 rm) --
// EPI 0: silu -> bf16     EPI 1: +bias, col<1024 ? tanh : sigmoid -> bf16
// r8/r6 structure -- BEST MEASURED (gemm2 148.9us, 0 bank conflicts,
// MfmaUtil 40.5%): 8 waves (2M x 4N), 16x16x32 MFMA, BK=64, 128 KiB
// macro-dbuf, one barrier per K-tile, counted-lgkm in-wave pipeline,
// k-swept MFMA, staging spread across quadrants.
// Swizzle: 16B chunk c stored at c^(row&7) (pre-swizzled global source,
// linear glds dest, swizzled ds_read addr).
// NOTE r9 lesson: 32x32x16 MFMA shape broke the conflict-free layout
// (1.26e7 conflicts, -12%) -- do not switch shapes without re-deriving
// the phase-level bank pattern.

template <int EPI>
__global__ __launch_bounds__(512, 2) void gemm256(const u16* __restrict__ A,
                                                  const u16* __restrict__ Bt,
                                                  u16* __restrict__ Co,
                                                  const float* __restrict__ bias,
                                                  int M, int N, int K) {
  __shared__ char lds[131072];  // buf b: A at b*65536, B at b*65536+32768
  const int tid = threadIdx.x;
  const int lane = tid & 63;
  const int wid = tid >> 6;
  const int wr = wid >> 2;  // 0..1
  const int wc = wid & 3;   // 0..3

  // XCD-aware bijective swizzle (nwg = 512, %8 == 0)
  const int gx = gridDim.x;
  const int nwg = gx * gridDim.y;
  const int bid = blockIdx.y * gx + blockIdx.x;
  const int swz = (bid & 7) * (nwg >> 3) + (bid >> 3);
  const long bm = (long)(swz / gx) * 256;
  const long bn = (long)(swz % gx) * 256;

  const int NT = K >> 6;

  // ---- staging precompute ----
  const int r0 = tid >> 3, c0p = tid & 7;
  const int r1 = r0 + 64;
  const int gA0 = (r0 & 63) + ((r0 >> 6) << 7);
  const int gA1 = (r1 & 63) + ((r1 >> 6) << 7);
  const int gB0 = (r0 & 31) + ((r0 >> 5) << 6);
  const int gB1 = (r1 & 31) + ((r1 >> 5) << 6);
  const int cA0 = c0p ^ (r0 & 7);  // swizzled source chunk
  const size_t srcA0 = (size_t)(bm + gA0) * K + cA0 * 8;
  const size_t srcA1 = (size_t)(bm + gA1) * K + cA0 * 8;
  const size_t srcB0 = (size_t)(bn + gB0) * K + cA0 * 8;
  const size_t srcB1 = (size_t)(bn + gB1) * K + cA0 * 8;
  const int dstA0 = gA0 * 128 + c0p * 16;
  const int dstA1 = gA1 * 128 + c0p * 16;
  const int dstB0 = 32768 + gB0 * 128 + c0p * 16;
  const int dstB1 = 32768 + gB1 * 128 + c0p * 16;
  const size_t halfA = (size_t)64 * K;  // elements
  const size_t halfB = (size_t)32 * K;

  // stage one half-tile pair (2 glds): pair 0..3 = Ah0, Ah1, Bh0, Bh1
#define STAGE_P(buf, t, pair)                                                        \
  do {                                                                               \
    if ((pair) == 0) {                                                               \
      glds16(A + srcA0 + (size_t)(t) * 64, lds + (buf) * 65536 + dstA0);             \
      glds16(A + srcA1 + (size_t)(t) * 64, lds + (buf) * 65536 + dstA1);             \
    } else if ((pair) == 1) {                                                        \
      glds16(A + srcA0 + halfA + (size_t)(t) * 64,                                   \
             lds + (buf) * 65536 + dstA0 + 8192);                                    \
      glds16(A + srcA1 + halfA + (size_t)(t) * 64,                                   \
             lds + (buf) * 65536 + dstA1 + 8192);                                    \
    } else if ((pair) == 2) {                                                        \
      glds16(Bt + srcB0 + (size_t)(t) * 64, lds + (buf) * 65536 + dstB0);            \
      glds16(Bt + srcB1 + (size_t)(t) * 64, lds + (buf) * 65536 + dstB1);            \
    } else {                                                                         \
      glds16(Bt + srcB0 + halfB + (size_t)(t) * 64,                                  \
             lds + (buf) * 65536 + dstB0 + 4096);                                    \
      glds16(Bt + srcB1 + halfB + (size_t)(t) * 64,                                  \
             lds + (buf) * 65536 + dstB1 + 4096);                                    \
    }                                                                                \
  } while (0)

  // ---- ds_read bases (swizzled): chunk' = (kh*4 + (lane>>4)) ^ (lane&7) ----
  const int l15 = lane & 15, l3 = lane & 7, g4 = lane >> 4;
  const int aoff0 = (wr * 128 + l15) * 128 + ((g4 ^ l3) * 16);
  const int aoff1 = (wr * 128 + l15) * 128 + (((4 + g4) ^ l3) * 16);
  const int boff0 = 32768 + (wc * 64 + l15) * 128 + ((g4 ^ l3) * 16);
  const int boff1 = 32768 + (wc * 64 + l15) * 128 + (((4 + g4) ^ l3) * 16);

  f32x4 acc[8][4] = {};

#define READ_A(dst, q)                                                               \
  do {                                                                               \
    dst[0][0] = *(const bf16x8*)(base + aoff0 + ((q) * 2 + 0) * 2048);               \
    dst[0][1] = *(const bf16x8*)(base + aoff1 + ((q) * 2 + 0) * 2048);               \
    dst[1][0] = *(const bf16x8*)(base + aoff0 + ((q) * 2 + 1) * 2048);               \
    dst[1][1] = *(const bf16x8*)(base + aoff1 + ((q) * 2 + 1) * 2048);               \
  } while (0)

  // k-swept: 8 independent kh=0 MFMAs, then 8 kh=1 (producer 8 instrs back)
#define MFMA_Q(q, af)                                                                \
  do {                                                                               \
    __builtin_amdgcn_s_setprio(1);                                                   \
    _Pragma("unroll") for (int kh = 0; kh < 2; ++kh)                                 \
        _Pragma("unroll") for (int mm = 0; mm < 2; ++mm)                             \
            _Pragma("unroll") for (int nn = 0; nn < 4; ++nn) {                       \
      acc[(q) * 2 + mm][nn] = __builtin_amdgcn_mfma_f32_16x16x32_bf16(               \
          af[mm][kh], bfr[nn][kh], acc[(q) * 2 + mm][nn], 0, 0, 0);                  \
    }                                                                                \
    __builtin_amdgcn_s_setprio(0);                                                   \
  } while (0)

  // ---- prologue: stage tile 0 into buf 0 ----
  STAGE_P(0, 0, 0);
  STAGE_P(0, 0, 1);
  STAGE_P(0, 0, 2);
  STAGE_P(0, 0, 3);
  VMCNT(0);
  FENCE_MEM();
  BAR();
  FENCE_MEM();

  for (int t = 0; t < NT; ++t) {
    const int p = t & 1;
    const char* base = lds + p * 65536;
    const bool s1 = (t + 1) < NT;

    bf16x8 bfr[4][2];
    bf16x8 afx[2][2], afy[2][2];  // named double-buffer (static idx, rule #20)

    // issue B all (8 ds_read) + A q0 (4) + A q1 (4)  -> 16 outstanding
#pragma unroll
    for (int nn = 0; nn < 4; ++nn) {
      bfr[nn][0] = *(const bf16x8*)(base + boff0 + nn * 2048);
      bfr[nn][1] = *(const bf16x8*)(base + boff1 + nn * 2048);
    }
    READ_A(afx, 0);
    READ_A(afy, 1);
    if (s1) STAGE_P(p ^ 1, t + 1, 0);
    FENCE_MEM();
    LGKMW(4);        // B + A0 complete; A1 in flight
    MFMA_Q(0, afx);
    READ_A(afx, 2);  // issue under q0 completion window
    if (s1) STAGE_P(p ^ 1, t + 1, 1);
    FENCE_MEM();
    LGKMW(4);        // A1 complete; A2 in flight
    MFMA_Q(1, afy);
    READ_A(afy, 3);
    if (s1) STAGE_P(p ^ 1, t + 1, 2);
    FENCE_MEM();
    LGKMW(4);        // A2 complete; A3 in flight
    MFMA_Q(2, afx);
    if (s1) STAGE_P(p ^ 1, t + 1, 3);
    FENCE_MEM();
    LGKMW(0);        // A3 complete
    MFMA_Q(3, afy);

    // tile end: next tile's stage loads must be in LDS before any wave
    // reads buf p^1
    VMCNT(0);
    FENCE_MEM();
    BAR();
    FENCE_MEM();
  }

  // ---- epilogue ----
  const int erow = (lane >> 4) * 4;
  const int ecol = lane & 15;
#pragma unroll
  for (int mf = 0; mf < 8; ++mf) {
#pragma unroll
    for (int nf = 0; nf < 4; ++nf) {
      const long col = bn + wc * 64 + nf * 16 + ecol;
      float badd = (EPI == 1) ? bias[col] : 0.f;
#pragma unroll
      for (int j = 0; j < 4; ++j) {
        const long row = bm + wr * 128 + mf * 16 + erow + j;
        float v = acc[mf][nf][j];
        if (EPI == 0) {
          v = fsilu(v);
        } else {
          v += badd;
          v = (col < 1024) ? ftanh(v) : fsigmoid(v);
        }
        Co[row * (long)N + col] = f2bf(v);
      }
    }
  }
#undef STAGE_P
#undef READ_A
#undef MFMA_Q
}

// ---------------- gated scan (3-pass chunked, r8-proven) ----------------
// sa layout: (B*T) x 2048 bf16; [.,0:1024)=tanh(theta), [.,1024:2048)=sigmoid(alpha)
// stage1 (scalar, 262144 threads -- TLP hides strided-access latency; the
// r9 4d/thread variant at 65536 threads measured SLOWER):
//   per (b,chunk,d) 64-step affine summary (A,B) and 63-step (A63,B63).
// stage2: tiny per-channel chunk scan -> hstart.
// scan3_fused: replay + conv + silu + residual + LN + L2.

__global__ __launch_bounds__(256) void scan_stage1(const u16* __restrict__ sa,
                                                   float* __restrict__ cA,
                                                   float* __restrict__ cB,
                                                   float* __restrict__ cA63,
                                                   float* __restrict__ cB63) {
  const int tid = blockIdx.x * 256 + threadIdx.x;  // 0..262143
  const int d = tid & 1023;
  const int chunk = (tid >> 10) & 63;
  const int b = tid >> 16;
  const size_t base = ((size_t)(b * 4096 + chunk * 64)) * 2048 + d;
  float Ac = 1.f, Bc = 0.f;
#pragma unroll 4
  for (int t = 0; t < 63; ++t) {
    float s = bf2f(sa[base + (size_t)t * 2048]);
    float a = bf2f(sa[base + (size_t)t * 2048 + 1024]);
    Bc = a * Bc + (1.f - a) * s;
    Ac *= a;
  }
  cA63[tid] = Ac;
  cB63[tid] = Bc;
  {
    float s = bf2f(sa[base + (size_t)63 * 2048]);
    float a = bf2f(sa[base + (size_t)63 * 2048 + 1024]);
    Bc = a * Bc + (1.f - a) * s;
    Ac *= a;
  }
  cA[tid] = Ac;
  cB[tid] = Bc;
}

__global__ __launch_bounds__(256) void scan_stage2(const float* __restrict__ cA,
                                                   const float* __restrict__ cB,
                                                   float* __restrict__ hstart) {
  const int tid = blockIdx.x * 256 + threadIdx.x;  // 0..4095
  const int d = tid & 1023;
  const int b = tid >> 10;
  float h = 0.f;
  for (int c = 0; c < 64; ++c) {
    const size_t i = ((size_t)(b * 64 + c)) * 1024 + d;
    hstart[i] = h;
    h = cA[i] * h + cB[i];
  }
}

// Fused: replay scan + causal depthwise conv(k=3) + silu + residual + LN + L2.
// Block = (b, chunk): 256 threads x 4 d each = 1024 channels, 64 rows.
// Conv taps h[t-1], h[t-2] in registers; chunk-boundary taps from hstart[c]
// and h[c*64-2] = A63[c-1]*hstart[c-1] + B63[c-1].
// LN+L2 in ONE 5-value block reduction per row:
//   nrm^2 = rstd^2*(G2-2mu G1+mu^2 Sg2) + 2 rstd*(GB-mu Sgb) + Sb2.
__global__ __launch_bounds__(256) void scan3_fused(
    const u16* __restrict__ sa, const float* __restrict__ hstart,
    const float* __restrict__ cA63, const float* __restrict__ cB63,
    const float* __restrict__ cw, const float* __restrict__ gamma,
    const float* __restrict__ beta, float* __restrict__ out) {
  const int blk = blockIdx.x;  // b*64 + c, 0..255
  const int c = blk & 63;
  const int tid = threadIdx.x;
  const int lane = tid & 63, wid = tid >> 6;
  const int d0 = tid * 4;
  const size_t m0 = (size_t)(blk >> 6) * 4096 + (size_t)c * 64;

  __shared__ float red[4][8];

  // per-thread params
  const float4 gv = *(const float4*)(gamma + d0);
  const float4 bv = *(const float4*)(beta + d0);
  const float g[4] = {gv.x, gv.y, gv.z, gv.w};
  const float be[4] = {bv.x, bv.y, bv.z, bv.w};
  float w0[4], w1[4], w2[4];
#pragma unroll
  for (int j = 0; j < 4; ++j) {
    w0[j] = cw[(d0 + j) * 3];
    w1[j] = cw[(d0 + j) * 3 + 1];
    w2[j] = cw[(d0 + j) * 3 + 2];
  }

  // chain boundary state: h1v = h[t0-1], h2v = h[t0-2]
  const size_t hidx = (size_t)blk * 1024 + d0;
  const float4 hs = *(const float4*)(hstart + hidx);
  float h1v[4] = {hs.x, hs.y, hs.z, hs.w};
  float h2v[4] = {0.f, 0.f, 0.f, 0.f};
  if (c > 0) {
    const float4 hp = *(const float4*)(hstart + hidx - 1024);
    const float4 a63 = *(const float4*)(cA63 + hidx - 1024);
    const float4 b63 = *(const float4*)(cB63 + hidx - 1024);
    h2v[0] = a63.x * hp.x + b63.x;
    h2v[1] = a63.y * hp.y + b63.y;
    h2v[2] = a63.z * hp.z + b63.z;
    h2v[3] = a63.w * hp.w + b63.w;
  }

  // block constants Sg2, Sgb, Sb2 (one 3-value reduction)
  float sg2 = 0.f, sgb = 0.f, sb2 = 0.f;
#pragma unroll
  for (int j = 0; j < 4; ++j) {
    sg2 += g[j] * g[j];
    sgb += g[j] * be[j];
    sb2 += be[j] * be[j];
  }
#pragma unroll
  for (int o = 32; o > 0; o >>= 1) {
    sg2 += __shfl_down(sg2, o);
    sgb += __shfl_down(sgb, o);
    sb2 += __shfl_down(sb2, o);
  }
  if (lane == 0) { red[wid][5] = sg2; red[wid][6] = sgb; red[wid][7] = sb2; }
  __syncthreads();
  const float Sg2 = red[0][5] + red[1][5] + red[2][5] + red[3][5];
  const float Sgb = red[0][6] + red[1][6] + red[2][6] + red[3][6];
  const float Sb2 = red[0][7] + red[1][7] + red[2][7] + red[3][7];
  __syncthreads();

  const u16* ps = sa + m0 * 2048 + d0;
  ushort4 sv = *(const ushort4*)(ps);
  ushort4 av = *(const ushort4*)(ps + 1024);

  for (int t = 0; t < 64; ++t) {
    ushort4 svn, avn;
    if (t + 1 < 64) {
      svn = *(const ushort4*)(ps + (size_t)(t + 1) * 2048);
      avn = *(const ushort4*)(ps + (size_t)(t + 1) * 2048 + 1024);
    }
    const float sarr[4] = {bf2f(sv.x), bf2f(sv.y), bf2f(sv.z), bf2f(sv.w)};
    const float aarr[4] = {bf2f(av.x), bf2f(av.y), bf2f(av.z), bf2f(av.w)};
    float y[4];
    float s1 = 0.f, s2 = 0.f, g1 = 0.f, g2 = 0.f, gb = 0.f;
#pragma unroll
    for (int j = 0; j < 4; ++j) {
      const float a = aarr[j];
      const float h = a * h1v[j] + (1.f - a) * sarr[j];
      float cb = w0[j] * h2v[j] + w1[j] * h1v[j] + w2[j] * h;
      cb = fsilu(cb);
      y[j] = h + 0.1f * cb;
      h2v[j] = h1v[j];
      h1v[j] = h;
      s1 += y[j];
      s2 += y[j] * y[j];
      const float gy = g[j] * y[j];
      g1 += g[j] * gy;
      g2 += gy * gy;
      gb += be[j] * gy;
    }
    // one 5-value block reduction
    float v0 = s1, v1 = s2, v2 = g1, v3 = g2, v4 = gb;
#pragma unroll
    for (int o = 32; o > 0; o >>= 1) {
      v0 += __shfl_down(v0, o);
      v1 += __shfl_down(v1, o);
      v2 += __shfl_down(v2, o);
      v3 += __shfl_down(v3, o);
      v4 += __shfl_down(v4, o);
    }
    if (lane == 0) {
      red[wid][0] = v0; red[wid][1] = v1; red[wid][2] = v2;
      red[wid][3] = v3; red[wid][4] = v4;
    }
    __syncthreads();
    const float S1 = red[0][0] + red[1][0] + red[2][0] + red[3][0];
    const float S2 = red[0][1] + red[1][1] + red[2][1] + red[3][1];
    const float G1 = red[0][2] + red[1][2] + red[2][2] + red[3][2];
    const float G2 = red[0][3] + red[1][3] + red[2][3] + red[3][3];
    const float GB = red[0][4] + red[1][4] + red[2][4] + red[3][4];
    const float mu = S1 * (1.f / 1024.f);
    const float var = S2 * (1.f / 1024.f) - mu * mu;
    const float rstd = rsqrtf(var + 1e-5f);
    const float sge2 = G2 - 2.f * mu * G1 + mu * mu * Sg2;
    const float sgbe = GB - mu * Sgb;
    const float nrm2 = rstd * rstd * sge2 + 2.f * rstd * sgbe + Sb2;
    const float nrm = sqrtf(fmaxf(nrm2, 0.f));
    const float scale = 1.f / fmaxf(nrm, 1e-12f);
    float4 o4;
    o4.x = (g[0] * (y[0] - mu) * rstd + be[0]) * scale;
    o4.y = (g[1] * (y[1] - mu) * rstd + be[1]) * scale;
    o4.z = (g[2] * (y[2] - mu) * rstd + be[2]) * scale;
    o4.w = (g[3] * (y[3] - mu) * rstd + be[3]) * scale;
    *(float4*)(out + (m0 + t) * 1024 + d0) = o4;
    __syncthreads();  // protect red[] before next row's writes
    sv = svn;
    av = avn;
  }
}

// ---------------- launch ----------------

extern "C" void kernel_launch(void* const* d_in, const int* in_sizes, int n_in,
                              void* d_out, int out_size, void* d_ws, size_t ws_size,
                              hipStream_t stream) {
  const float* x = (const float*)d_in[0];
  const float* W1 = (const float*)d_in[1];
  const float* W2 = (const float*)d_in[2];
  const float* b2 = (const float*)d_in[3];
  const float* cw = (const float*)d_in[4];
  const float* gamma = (const float*)d_in[5];
  const float* beta = (const float*)d_in[6];
  float* out = (float*)d_out;
  char* ws = (char*)d_ws;

  // workspace layout (bytes):
  // [0,32M)    xb (bf16 x) -- dead after gemm1; reused by scan buffers:
  //            cA@0, cB@1M, hstart@2M, cA63@3M, cB63@4M (each 1MB)
  // [32M,36M)  w1t   [36M,44M) w2t
  // [44M,108M) h1 (bf16 16384x2048) -- gemm2 input
  // [108M,172M) sa (bf16 16384x2048) tanh(theta) | sigmoid(alpha)
  u16* xb = (u16*)(ws);
  u16* w1t = (u16*)(ws + 33554432);
  u16* w2t = (u16*)(ws + 37748736);
  u16* h1 = (u16*)(ws + 46137344);
  u16* sa = (u16*)(ws + 113246208);
  float* cA = (float*)(ws);
  float* cB = (float*)(ws + 1048576);
  float* hstart = (float*)(ws + 2097152);
  float* cA63 = (float*)(ws + 3145728);
  float* cB63 = (float*)(ws + 4194304);

  cast_bf16_vec<<<16384, 256, 0, stream>>>(x, xb, 4194304);
  transpose_cast<<<dim3(64, 32), dim3(32, 8), 0, stream>>>(W1, w1t, 1024, 2048);
  transpose_cast<<<dim3(64, 64), dim3(32, 8), 0, stream>>>(W2, w2t, 2048, 2048);
  gemm256<0><<<dim3(8, 64), 512, 0, stream>>>(xb, w1t, h1, nullptr, 16384, 2048, 1024);
  gemm256<1><<<dim3(8, 64), 512, 0, stream>>>(h1, w2t, sa, b2, 16384, 2048, 2048);
  scan_stage1<<<1024, 256, 0, stream>>>(sa, cA, cB, cA63, cB63);
  scan_stage2<<<16, 256, 0, stream>>>(cA, cB, hstart);
  scan3_fused<<<256, 256, 0, stream>>>(sa, hstart, cA63, cB63, cw, gamma, beta, out);
}